// Round 7
// baseline (55.238 us; speedup 1.0000x reference)
//
#include <hip/hip_runtime.h>
#include <hip/hip_bf16.h>

#define NUM_GT 25
#define NUM_PRED 40
#define PAD 32         // 128 B between global words

// ws u32 word offsets (each on its own 128B line):
//   GT_W(b), b=0..24 : g_gt(b) = sum |gt - b|     (SAD accumulators)
//   PR_W(p), p=0..39 : g_pr(p) = sum |pred - p|
//   OV_W(p), p=0..40 : overlap bitmask row p
#define GT_W(b)  ((b) * PAD)
#define PR_W(p)  ((25 + (p)) * PAD)
#define OV_W(p)  ((65 + (p)) * PAD)
#define WS_WORDS (106 * PAD)

#define GRID 2048
#define BLOCK 256

// ---------------------------------------------------------------------------
// SAD histogram, MLP-optimized: 2 adjacent quads (8 voxels, 64 B) per lane per
// iteration, all 4 dwordx4 loads issued up front; ONE overlap branch per iter
// (8 sovl bit-tests ANDed). count(x==B) = (g(B-1)-2g(B)+g(B+1))/2 recovered in
// the finisher; 65 v_sad_u8 accumulators pinned to VGPRs via asm "+v".
// ---------------------------------------------------------------------------
__global__ __launch_bounds__(BLOCK, 4) void hist_kernel(
    const float* __restrict__ pred, const int* __restrict__ gt,
    unsigned int* __restrict__ ws, int n)
{
    __shared__ unsigned int sovl[64];        // overlap rows, test-then-set
    __shared__ unsigned int shist[65];       // per-block bin totals
    __shared__ unsigned int stash[4][16][34];// epilogue scratch

    const int tid  = threadIdx.x;
    const int lane = tid & 63;
    const int wave = tid >> 6;

    if (tid < 64) sovl[tid] = 0u;
    if (tid < 65) shist[tid] = 0u;
    __syncthreads();

    // acc[0..24] = g_gt(0..24); acc[25..64] = g_pr(0..39); acc[65] dummy
    unsigned acc[66];
    #pragma unroll
    for (int j = 0; j < 66; ++j) acc[j] = 0u;

    const int gtid    = blockIdx.x * BLOCK + tid;
    const int stride2 = GRID * BLOCK * 2;    // quads per sweep
    const int n4 = n >> 2;

    const float4* __restrict__ p4 = (const float4*)pred;
    const int4* __restrict__  g4 = (const int4*)gt;

    for (int q = gtid * 2; q + 1 < n4; q += stride2) {
        // ---- 64 B/lane in flight: 4 x dwordx4, pairwise adjacent ----
        float4 pv0 = p4[q];
        float4 pv1 = p4[q + 1];
        int4  gv0 = g4[q];
        int4  gv1 = g4[q + 1];

        unsigned a0 = (unsigned)gv0.x, a1 = (unsigned)gv0.y;
        unsigned a2 = (unsigned)gv0.z, a3 = (unsigned)gv0.w;
        unsigned a4 = (unsigned)gv1.x, a5 = (unsigned)gv1.y;
        unsigned a6 = (unsigned)gv1.z, a7 = (unsigned)gv1.w;
        unsigned b0 = (unsigned)pv0.x, b1 = (unsigned)pv0.y;
        unsigned b2 = (unsigned)pv0.z, b3 = (unsigned)pv0.w;
        unsigned b4 = (unsigned)pv1.x, b5 = (unsigned)pv1.y;
        unsigned b6 = (unsigned)pv1.z, b7 = (unsigned)pv1.w;

        // ---- single overlap test: AND of 8 shifted rows, bit0 = all seen ----
        unsigned ok = (sovl[b0 & 63] >> (a0 & 31)) & (sovl[b1 & 63] >> (a1 & 31))
                    & (sovl[b2 & 63] >> (a2 & 31)) & (sovl[b3 & 63] >> (a3 & 31))
                    & (sovl[b4 & 63] >> (a4 & 31)) & (sovl[b5 & 63] >> (a5 & 31))
                    & (sovl[b6 & 63] >> (a6 & 31)) & (sovl[b7 & 63] >> (a7 & 31));
        if (!(ok & 1u)) {                    // rare after warm-up
            atomicOr(&sovl[b0 & 63], 1u << (a0 & 31));
            atomicOr(&sovl[b1 & 63], 1u << (a1 & 31));
            atomicOr(&sovl[b2 & 63], 1u << (a2 & 31));
            atomicOr(&sovl[b3 & 63], 1u << (a3 & 31));
            atomicOr(&sovl[b4 & 63], 1u << (a4 & 31));
            atomicOr(&sovl[b5 & 63], 1u << (a5 & 31));
            atomicOr(&sovl[b6 & 63], 1u << (a6 & 31));
            atomicOr(&sovl[b7 & 63], 1u << (a7 & 31));
        }

        // ---- byte-pack 8 voxels into 4 words ----
        unsigned GA = a0 | (a1 << 8) | (a2 << 16) | (a3 << 24);
        unsigned GB = a4 | (a5 << 8) | (a6 << 16) | (a7 << 24);
        unsigned PA = b0 | (b1 << 8) | (b2 << 16) | (b3 << 24);
        unsigned PB = b4 | (b5 << 8) | (b6 << 16) | (b7 << 24);

        // ---- 65 bins x 2 SADs (independent across bins -> full ILP) ----
        #pragma unroll
        for (int b = 0; b < 25; ++b) {
            asm("v_sad_u8 %0, %1, %2, %0"
                : "+v"(acc[b]) : "v"(GA), "s"((unsigned)(b * 0x01010101u)));
            asm("v_sad_u8 %0, %1, %2, %0"
                : "+v"(acc[b]) : "v"(GB), "s"((unsigned)(b * 0x01010101u)));
        }
        #pragma unroll
        for (int b = 0; b < 40; ++b) {
            asm("v_sad_u8 %0, %1, %2, %0"
                : "+v"(acc[25 + b]) : "v"(PA), "s"((unsigned)(b * 0x01010101u)));
            asm("v_sad_u8 %0, %1, %2, %0"
                : "+v"(acc[25 + b]) : "v"(PB), "s"((unsigned)(b * 0x01010101u)));
        }
    }

    // leftover voxels (none for n = 256^3; defensive, SAD semantics)
    if (blockIdx.x == 0 && tid == 0) {
        for (int v = (n4 & ~1) << 2; v < n; ++v) {
            int p = (int)pred[v];
            int g = gt[v];
            for (int b = 0; b < 25; ++b) atomicAdd(&ws[GT_W(b)], (unsigned)abs(g - b));
            for (int b = 0; b < 40; ++b) atomicAdd(&ws[PR_W(b)], (unsigned)abs(p - b));
            atomicOr(&ws[OV_W(min(max(p, 0), NUM_PRED))], 1u << (g & 31));
        }
    }

    // ---- epilogue: pair-packed u16 tree (per-lane acc <= 32*40 = 1280) ----
    #pragma unroll
    for (int jp = 0; jp < 33; ++jp) {
        unsigned v = acc[2 * jp] | (acc[2 * jp + 1] << 16);
        v += __shfl_down(v, 32, 64);          // halves <= 2560
        v += __shfl_down(v, 16, 64);          // halves <= 5120
        if (lane < 16) stash[wave][lane][jp] = v;
    }
    __syncthreads();

    for (int i = tid; i < 33 * 16; i += BLOCK) {
        int jp = i >> 4, sl = i & 15;
        unsigned a = stash[0][sl][jp] + stash[1][sl][jp]
                   + stash[2][sl][jp] + stash[3][sl][jp];   // halves <= 20480
        unsigned lo = a & 0xFFFFu, hi = a >> 16;
        lo += __shfl_down(lo, 8, 16);  hi += __shfl_down(hi, 8, 16);
        lo += __shfl_down(lo, 4, 16);  hi += __shfl_down(hi, 4, 16);
        lo += __shfl_down(lo, 2, 16);  hi += __shfl_down(hi, 2, 16);
        lo += __shfl_down(lo, 1, 16);  hi += __shfl_down(hi, 1, 16);
        if (sl == 0) {
            if (lo) atomicAdd(&shist[2 * jp], lo);
            if (hi && 2 * jp + 1 < 65) atomicAdd(&shist[2 * jp + 1], hi);
        }
    }
    __syncthreads();

    for (int i = tid; i < 65; i += BLOCK) {
        unsigned s = shist[i];
        if (s) atomicAdd(&ws[i * PAD], s);
    }
    if (tid < 41) {
        unsigned v = sovl[tid];
        if (v) atomicOr(&ws[OV_W(tid)], v);
    }
}

// ---------------------------------------------------------------------------
// Finisher: second-difference count extraction (exact int64) + dice (fp64).
// ---------------------------------------------------------------------------
__global__ __launch_bounds__(64) void finish_kernel(
    const unsigned int* __restrict__ ws, float* __restrict__ out, int n)
{
    __shared__ long long gg[25], gp[40], psz[41];
    __shared__ unsigned ov[41];
    const int lane = threadIdx.x;
    if (lane < 25) gg[lane] = (long long)ws[GT_W(lane)];
    if (lane < 40) gp[lane] = (long long)ws[PR_W(lane)];
    if (lane < 41) ov[lane] = ws[OV_W(lane)];
    __syncthreads();

    const long long N = n, Sg = gg[0], Sp = gp[0];

    if (lane < 41) {                         // pred_sizes[P], P = lane
        int P = lane;
        long long f;
        if (P == 0)       f = (N - gp[0] + gp[1]) / 2;
        else if (P <= 38) f = (gp[P - 1] - 2 * gp[P] + gp[P + 1]) / 2;
        else if (P == 39) f = (gp[38] - 2 * gp[39] + (40 * N - Sp)) / 2;
        else              f = (gp[39] - 39 * N + Sp) / 2;   // P = 40
        psz[P] = f;
    }
    __syncthreads();

    double dice = 0.0;
    int present = 0;
    if (lane < 25) {                         // gt component label L = lane+1
        int L = lane + 1;
        long long gs;
        if (L <= 23)      gs = (gg[L - 1] - 2 * gg[L] + gg[L + 1]) / 2;
        else if (L == 24) gs = (gg[23] - 2 * gg[24] + (25 * N - Sg)) / 2;
        else              gs = (gg[24] - 24 * N + Sg) / 2;  // L = 25
        if (gs > 0) {
            present = 1;
            double un = 0.0;
            const unsigned bit = 1u << L;
            for (int p = 0; p < 41; ++p)
                if (ov[p] & bit) un += (double)psz[p];
            dice = 2.0 * (double)gs / (un + (double)gs + 1.0);
        }
    }
    int fp = 0;
    if (lane < 41) {
        if (psz[lane] > 0 && (ov[lane] & 0x3FFFFFEu) == 0) fp = 1;
    }

    int num_gt = __popcll(__ballot(present != 0));
    int nfp    = __popcll(__ballot(fp != 0));
    #pragma unroll
    for (int o = 32; o >= 1; o >>= 1) dice += __shfl_xor(dice, o, 64);

    if (lane == 0) out[0] = (float)(dice / (double)(num_gt + nfp));
}

extern "C" void kernel_launch(void* const* d_in, const int* in_sizes, int n_in,
                              void* d_out, int out_size, void* d_ws, size_t ws_size,
                              hipStream_t stream) {
    const float* pred = (const float*)d_in[0];
    const int* gt = (const int*)d_in[1];
    float* out = (float*)d_out;
    unsigned int* ws = (unsigned int*)d_ws;
    const int n = in_sizes[0];

    hipMemsetAsync(ws, 0, WS_WORDS * sizeof(unsigned int), stream);

    hist_kernel<<<GRID, BLOCK, 0, stream>>>(pred, gt, ws, n);
    finish_kernel<<<1, 64, 0, stream>>>(ws, out, n);
}

// Round 8
// 48.042 us; speedup vs baseline: 1.1498x; 1.1498x over previous
//
#include <hip/hip_runtime.h>
#include <hip/hip_bf16.h>

#define NUM_GT 25
#define NUM_PRED 40
#define PAD 32         // 128 B between global words

// ws u32 word offsets (each on its own 128B line):
//   GT_W(b), b=0..24 : g_gt(b) = sum |gt - b|     (SAD accumulators)
//   PR_W(p), p=0..39 : g_pr(p) = sum |pred - p|
//   OV_W(p), p=0..40 : overlap bitmask row p
#define GT_W(b)  ((b) * PAD)
#define PR_W(p)  ((25 + (p)) * PAD)
#define OV_W(p)  ((65 + (p)) * PAD)
#define WS_WORDS (106 * PAD)

#define GRID 1024
#define BLOCK 256

// ---------------------------------------------------------------------------
// SAD histogram with an EXPLICIT 1-deep load pipeline (manual double buffer,
// named registers per rule-of-thumb "no runtime-indexed buffers"):
//   iter i: issue 4 dwordx4 loads for iter i+1 (unconditional, clamped addr)
//           -> 130 v_sad_u8 on buffer A -> rotate B->A (vmcnt wait lands HERE,
//           after compute, so HBM/L2 latency overlaps the SAD block).
// count(x==B) = (g(B-1)-2g(B)+g(B+1))/2 recovered in the finisher.
// ---------------------------------------------------------------------------
__global__ __launch_bounds__(BLOCK, 4) void hist_kernel(
    const float* __restrict__ pred, const int* __restrict__ gt,
    unsigned int* __restrict__ ws, int n)
{
    __shared__ unsigned int sovl[64];        // overlap rows, test-then-set
    __shared__ unsigned int shist[65];       // per-block bin totals
    __shared__ unsigned int stash[4][16][34];// epilogue scratch

    const int tid  = threadIdx.x;
    const int lane = tid & 63;
    const int wave = tid >> 6;

    if (tid < 64) sovl[tid] = 0u;
    if (tid < 65) shist[tid] = 0u;
    __syncthreads();

    // acc[0..24] = g_gt(0..24); acc[25..64] = g_pr(0..39); acc[65] dummy
    unsigned acc[66];
    #pragma unroll
    for (int j = 0; j < 66; ++j) acc[j] = 0u;

    const int gtid = blockIdx.x * BLOCK + tid;
    const int n4   = n >> 2;
    const int step = GRID * BLOCK * 2;       // quads consumed per iteration
    const int nit  = n4 / step;              // uniform full iterations (8 here)

    const float4* __restrict__ p4 = (const float4*)pred;
    const int4* __restrict__  g4 = (const int4*)gt;

    // ---- 8-voxel processing macro (2 quads) ----
    #define PROC8(PV0, PV1, GV0, GV1)                                          \
    do {                                                                       \
        unsigned a0 = (unsigned)(GV0).x, a1 = (unsigned)(GV0).y;               \
        unsigned a2 = (unsigned)(GV0).z, a3 = (unsigned)(GV0).w;               \
        unsigned a4 = (unsigned)(GV1).x, a5 = (unsigned)(GV1).y;               \
        unsigned a6 = (unsigned)(GV1).z, a7 = (unsigned)(GV1).w;               \
        unsigned b0 = (unsigned)(PV0).x, b1 = (unsigned)(PV0).y;               \
        unsigned b2 = (unsigned)(PV0).z, b3 = (unsigned)(PV0).w;               \
        unsigned b4 = (unsigned)(PV1).x, b5 = (unsigned)(PV1).y;               \
        unsigned b6 = (unsigned)(PV1).z, b7 = (unsigned)(PV1).w;               \
        unsigned ok = (sovl[b0 & 63] >> (a0 & 31)) & (sovl[b1 & 63] >> (a1 & 31)) \
                    & (sovl[b2 & 63] >> (a2 & 31)) & (sovl[b3 & 63] >> (a3 & 31)) \
                    & (sovl[b4 & 63] >> (a4 & 31)) & (sovl[b5 & 63] >> (a5 & 31)) \
                    & (sovl[b6 & 63] >> (a6 & 31)) & (sovl[b7 & 63] >> (a7 & 31)); \
        if (!(ok & 1u)) {                                                      \
            atomicOr(&sovl[b0 & 63], 1u << (a0 & 31));                         \
            atomicOr(&sovl[b1 & 63], 1u << (a1 & 31));                         \
            atomicOr(&sovl[b2 & 63], 1u << (a2 & 31));                         \
            atomicOr(&sovl[b3 & 63], 1u << (a3 & 31));                         \
            atomicOr(&sovl[b4 & 63], 1u << (a4 & 31));                         \
            atomicOr(&sovl[b5 & 63], 1u << (a5 & 31));                         \
            atomicOr(&sovl[b6 & 63], 1u << (a6 & 31));                         \
            atomicOr(&sovl[b7 & 63], 1u << (a7 & 31));                         \
        }                                                                      \
        unsigned GA = a0 | (a1 << 8) | (a2 << 16) | (a3 << 24);                \
        unsigned GB = a4 | (a5 << 8) | (a6 << 16) | (a7 << 24);                \
        unsigned PA = b0 | (b1 << 8) | (b2 << 16) | (b3 << 24);                \
        unsigned PB = b4 | (b5 << 8) | (b6 << 16) | (b7 << 24);                \
        _Pragma("unroll")                                                      \
        for (int b = 0; b < 25; ++b) {                                         \
            asm("v_sad_u8 %0, %1, %2, %0"                                      \
                : "+v"(acc[b]) : "v"(GA), "s"((unsigned)(b * 0x01010101u)));   \
            asm("v_sad_u8 %0, %1, %2, %0"                                      \
                : "+v"(acc[b]) : "v"(GB), "s"((unsigned)(b * 0x01010101u)));   \
        }                                                                      \
        _Pragma("unroll")                                                      \
        for (int b = 0; b < 40; ++b) {                                         \
            asm("v_sad_u8 %0, %1, %2, %0"                                      \
                : "+v"(acc[25+b]) : "v"(PA), "s"((unsigned)(b * 0x01010101u)));\
            asm("v_sad_u8 %0, %1, %2, %0"                                      \
                : "+v"(acc[25+b]) : "v"(PB), "s"((unsigned)(b * 0x01010101u)));\
        }                                                                      \
    } while (0)

    // ---- explicit 1-deep pipelined main loop ----
    if (nit > 0) {
        int q = gtid * 2;
        float4 pA0 = p4[q], pA1 = p4[q + 1];
        int4  gA0 = g4[q], gA1 = g4[q + 1];
        for (int it = 0; it < nit; ++it) {
            // prefetch next batch; clamp address on last iter (result unused)
            const int qn = (it + 1 < nit) ? (q + step) : q;
            float4 pB0 = p4[qn], pB1 = p4[qn + 1];
            int4  gB0 = g4[qn], gB1 = g4[qn + 1];

            PROC8(pA0, pA1, gA0, gA1);

            // rotate: the vmcnt wait for the prefetch lands here, after compute
            pA0 = pB0; pA1 = pB1; gA0 = gB0; gA1 = gB1;
            q += step;
        }
    }

    // remainder quads (none when step | n4; defensive, unpipelined)
    for (int qq = nit * step + gtid; qq < n4; qq += GRID * BLOCK) {
        float4 pv = p4[qq];
        int4  gv = g4[qq];
        unsigned a0 = (unsigned)gv.x, a1 = (unsigned)gv.y;
        unsigned a2 = (unsigned)gv.z, a3 = (unsigned)gv.w;
        unsigned b0 = (unsigned)pv.x, b1 = (unsigned)pv.y;
        unsigned b2 = (unsigned)pv.z, b3 = (unsigned)pv.w;
        unsigned ok = (sovl[b0 & 63] >> (a0 & 31)) & (sovl[b1 & 63] >> (a1 & 31))
                    & (sovl[b2 & 63] >> (a2 & 31)) & (sovl[b3 & 63] >> (a3 & 31));
        if (!(ok & 1u)) {
            atomicOr(&sovl[b0 & 63], 1u << (a0 & 31));
            atomicOr(&sovl[b1 & 63], 1u << (a1 & 31));
            atomicOr(&sovl[b2 & 63], 1u << (a2 & 31));
            atomicOr(&sovl[b3 & 63], 1u << (a3 & 31));
        }
        unsigned GA = a0 | (a1 << 8) | (a2 << 16) | (a3 << 24);
        unsigned PA = b0 | (b1 << 8) | (b2 << 16) | (b3 << 24);
        #pragma unroll
        for (int b = 0; b < 25; ++b)
            asm("v_sad_u8 %0, %1, %2, %0"
                : "+v"(acc[b]) : "v"(GA), "s"((unsigned)(b * 0x01010101u)));
        #pragma unroll
        for (int b = 0; b < 40; ++b)
            asm("v_sad_u8 %0, %1, %2, %0"
                : "+v"(acc[25+b]) : "v"(PA), "s"((unsigned)(b * 0x01010101u)));
    }

    // scalar tail for n % 4 (none here; defensive, SAD semantics)
    if (blockIdx.x == 0 && tid == 0) {
        for (int v = n4 << 2; v < n; ++v) {
            int p = (int)pred[v];
            int g = gt[v];
            for (int b = 0; b < 25; ++b) atomicAdd(&ws[GT_W(b)], (unsigned)abs(g - b));
            for (int b = 0; b < 40; ++b) atomicAdd(&ws[PR_W(b)], (unsigned)abs(p - b));
            atomicOr(&ws[OV_W(min(max(p, 0), NUM_PRED))], 1u << (g & 31));
        }
    }

    // ---- epilogue: pair-packed u16 tree (per-lane acc <= 64 vox * 40 = 2560)
    #pragma unroll
    for (int jp = 0; jp < 33; ++jp) {
        unsigned v = acc[2 * jp] | (acc[2 * jp + 1] << 16);
        v += __shfl_down(v, 32, 64);          // halves <= 5120
        v += __shfl_down(v, 16, 64);          // halves <= 10240
        if (lane < 16) stash[wave][lane][jp] = v;
    }
    __syncthreads();

    for (int i = tid; i < 33 * 16; i += BLOCK) {
        int jp = i >> 4, sl = i & 15;
        unsigned a = stash[0][sl][jp] + stash[1][sl][jp]
                   + stash[2][sl][jp] + stash[3][sl][jp];   // halves <= 40960
        unsigned lo = a & 0xFFFFu, hi = a >> 16;
        lo += __shfl_down(lo, 8, 16);  hi += __shfl_down(hi, 8, 16);
        lo += __shfl_down(lo, 4, 16);  hi += __shfl_down(hi, 4, 16);
        lo += __shfl_down(lo, 2, 16);  hi += __shfl_down(hi, 2, 16);
        lo += __shfl_down(lo, 1, 16);  hi += __shfl_down(hi, 1, 16);
        if (sl == 0) {
            if (lo) atomicAdd(&shist[2 * jp], lo);
            if (hi && 2 * jp + 1 < 65) atomicAdd(&shist[2 * jp + 1], hi);
        }
    }
    __syncthreads();

    for (int i = tid; i < 65; i += BLOCK) {
        unsigned s = shist[i];
        if (s) atomicAdd(&ws[i * PAD], s);
    }
    if (tid < 41) {
        unsigned v = sovl[tid];
        if (v) atomicOr(&ws[OV_W(tid)], v);
    }
    #undef PROC8
}

// ---------------------------------------------------------------------------
// Finisher: second-difference count extraction (exact int64) + dice (fp64).
// ---------------------------------------------------------------------------
__global__ __launch_bounds__(64) void finish_kernel(
    const unsigned int* __restrict__ ws, float* __restrict__ out, int n)
{
    __shared__ long long gg[25], gp[40], psz[41];
    __shared__ unsigned ov[41];
    const int lane = threadIdx.x;
    if (lane < 25) gg[lane] = (long long)ws[GT_W(lane)];
    if (lane < 40) gp[lane] = (long long)ws[PR_W(lane)];
    if (lane < 41) ov[lane] = ws[OV_W(lane)];
    __syncthreads();

    const long long N = n, Sg = gg[0], Sp = gp[0];

    if (lane < 41) {                         // pred_sizes[P], P = lane
        int P = lane;
        long long f;
        if (P == 0)       f = (N - gp[0] + gp[1]) / 2;
        else if (P <= 38) f = (gp[P - 1] - 2 * gp[P] + gp[P + 1]) / 2;
        else if (P == 39) f = (gp[38] - 2 * gp[39] + (40 * N - Sp)) / 2;
        else              f = (gp[39] - 39 * N + Sp) / 2;   // P = 40
        psz[P] = f;
    }
    __syncthreads();

    double dice = 0.0;
    int present = 0;
    if (lane < 25) {                         // gt component label L = lane+1
        int L = lane + 1;
        long long gs;
        if (L <= 23)      gs = (gg[L - 1] - 2 * gg[L] + gg[L + 1]) / 2;
        else if (L == 24) gs = (gg[23] - 2 * gg[24] + (25 * N - Sg)) / 2;
        else              gs = (gg[24] - 24 * N + Sg) / 2;  // L = 25
        if (gs > 0) {
            present = 1;
            double un = 0.0;
            const unsigned bit = 1u << L;
            for (int p = 0; p < 41; ++p)
                if (ov[p] & bit) un += (double)psz[p];
            dice = 2.0 * (double)gs / (un + (double)gs + 1.0);
        }
    }
    int fp = 0;
    if (lane < 41) {
        if (psz[lane] > 0 && (ov[lane] & 0x3FFFFFEu) == 0) fp = 1;
    }

    int num_gt = __popcll(__ballot(present != 0));
    int nfp    = __popcll(__ballot(fp != 0));
    #pragma unroll
    for (int o = 32; o >= 1; o >>= 1) dice += __shfl_xor(dice, o, 64);

    if (lane == 0) out[0] = (float)(dice / (double)(num_gt + nfp));
}

extern "C" void kernel_launch(void* const* d_in, const int* in_sizes, int n_in,
                              void* d_out, int out_size, void* d_ws, size_t ws_size,
                              hipStream_t stream) {
    const float* pred = (const float*)d_in[0];
    const int* gt = (const int*)d_in[1];
    float* out = (float*)d_out;
    unsigned int* ws = (unsigned int*)d_ws;
    const int n = in_sizes[0];

    hipMemsetAsync(ws, 0, WS_WORDS * sizeof(unsigned int), stream);

    hist_kernel<<<GRID, BLOCK, 0, stream>>>(pred, gt, ws, n);
    finish_kernel<<<1, 64, 0, stream>>>(ws, out, n);
}